// Round 1
// 38283.615 us; speedup vs baseline: 1.1522x; 1.1522x over previous
//
#include <hip/hip_runtime.h>
#include <hip/hip_bf16.h>

// LSTM persistent-kernel implementation for MI355X (gfx950).
// S=2048 sequential steps; 64 WGs (1/CU), WG j owns hidden slice [8j, 8j+8).
// Weights (32 gate rows x 1024 K) cached in LDS as bf16 for the whole kernel.
//
// R1 change: cross-WG h exchange + flags use RELAXED agent-scope atomics
// (sc1 write-through / L2-bypass) instead of threadfence+acquire. This
// removes the per-step buffer_wbl2 (whole-L2 writeback) and per-poll
// buffer_inv (whole-L2 invalidate) from the recurrence critical path.
// out[] stores moved after the flag publish (their drain overlaps the
// next step's x staging). cs stride padded 8->9 (bank spread).

#define SEQ 2048
#define BAT 64
#define DIN 512
#define HID 512
#define NWG 64
#define HS  8          // hidden units per WG
#define NG  32         // gate rows per WG (4*HS)
#define XSS 520        // xs row stride in bf16 elems (+8 pad: 4-bank row shift)
#define WSS 520
#define CSS 9          // cs row stride in floats (pad to break 8-way alias)

typedef short v8s __attribute__((ext_vector_type(8)));   // 8 x bf16 (4 VGPRs)
typedef float v4f __attribute__((ext_vector_type(4)));   // MFMA accumulator
typedef unsigned long long u64;

__device__ __forceinline__ unsigned short f2bf(float f) {
  unsigned int u = __builtin_bit_cast(unsigned int, f);
  u += 0x7fffu + ((u >> 16) & 1u);   // round-to-nearest-even
  return (unsigned short)(u >> 16);
}
__device__ __forceinline__ float sigm(float v)  { return 1.0f / (1.0f + __expf(-v)); }
__device__ __forceinline__ float tanha(float v) { return 1.0f - 2.0f / (__expf(2.0f * v) + 1.0f); }

__global__ __launch_bounds__(256, 1) void lstm_persistent(
    const float* __restrict__ x, const float* __restrict__ Wih,
    const float* __restrict__ Whh, const float* __restrict__ bih,
    const float* __restrict__ bhh, float* __restrict__ out,
    int* __restrict__ flags, unsigned short* __restrict__ hbuf)
{
  __shared__ unsigned short xs[BAT * XSS];     // 66,560 B: x_t or h_{t-1} as bf16
  __shared__ unsigned short Wx[NG * WSS];      // 33,280 B: W_ih slice
  __shared__ unsigned short Wh[NG * WSS];      // 33,280 B: W_hh slice
  __shared__ float gl[BAT * (NG + 1)];         //  8,448 B: gate pre-activations
  __shared__ float cs[BAT * CSS];              //  2,304 B: c state (fp32, padded)
  __shared__ float bias[NG];

  const int tid = threadIdx.x;
  const int j   = blockIdx.x;
  const int hb  = j * HS;

  // ---- one-time: load weight slices (rows: c = g*8+hh -> global row g*512+hb+hh) ----
  for (int idx = tid; idx < NG * 128; idx += 256) {
    int r = idx >> 7;              // 0..31
    int k = (idx & 127) * 4;       // 0..508
    int grow = (r >> 3) * HID + hb + (r & 7);
    float4 a = *(const float4*)(Wih + (size_t)grow * DIN + k);
    float4 b = *(const float4*)(Whh + (size_t)grow * HID + k);
    *(ushort4*)(Wx + r * WSS + k) = make_ushort4(f2bf(a.x), f2bf(a.y), f2bf(a.z), f2bf(a.w));
    *(ushort4*)(Wh + r * WSS + k) = make_ushort4(f2bf(b.x), f2bf(b.y), f2bf(b.z), f2bf(b.w));
  }
  if (tid < NG) {
    int grow = (tid >> 3) * HID + hb + (tid & 7);
    bias[tid] = bih[grow] + bhh[grow];
  }
  for (int i = tid; i < BAT * CSS; i += 256) cs[i] = 0.0f;
  __syncthreads();

  const int wv = tid >> 6, ln = tid & 63, l15 = ln & 15, lg = ln >> 4;
  const int m0 = wv * 16;        // wave owns batch rows [m0, m0+16)
  const unsigned short* aptr = xs + (m0 + l15) * XSS + lg * 8;

  for (int t = 0; t < SEQ; ++t) {
    // ---- stage x[t] -> xs as bf16 (coalesced float4 reads; L2 stays warm now) ----
    for (int it = tid; it < BAT * DIN / 4; it += 256) {
      int m = it >> 7;
      int k = (it & 127) * 4;
      float4 v = *(const float4*)(x + ((size_t)t * BAT + m) * DIN + k);
      *(ushort4*)(xs + m * XSS + k) = make_ushort4(f2bf(v.x), f2bf(v.y), f2bf(v.z), f2bf(v.w));
    }
    __syncthreads();

    v4f acc0 = {0.f, 0.f, 0.f, 0.f}, acc1 = {0.f, 0.f, 0.f, 0.f};
    // ---- phase X: gates += x_t @ W_ih_slice^T  (overlaps with h not yet ready) ----
    {
      const unsigned short* b0 = Wx + l15 * WSS + lg * 8;
      const unsigned short* b1 = Wx + (16 + l15) * WSS + lg * 8;
      #pragma unroll
      for (int kc = 0; kc < DIN; kc += 32) {
        v8s a  = *(const v8s*)(aptr + kc);
        v8s w0 = *(const v8s*)(b0 + kc);
        v8s w1 = *(const v8s*)(b1 + kc);
        acc0 = __builtin_amdgcn_mfma_f32_16x16x32_bf16(a, w0, acc0, 0, 0, 0);
        acc1 = __builtin_amdgcn_mfma_f32_16x16x32_bf16(a, w1, acc1, 0, 0, 0);
      }
    }
    if (t > 0) {
      // ---- wait for all 64 h-chunks of step t-1 (wave0 polls, one flag per lane).
      //      RELAXED agent loads: coherent read from L3, NO buffer_inv per poll. ----
      if (wv == 0) {
        int fidx = (t - 1) * NWG + ln;
        while (__hip_atomic_load(flags + fidx, __ATOMIC_RELAXED,
                                 __HIP_MEMORY_SCOPE_AGENT) != t) {
          __builtin_amdgcn_s_sleep(2);
        }
      }
      asm volatile("" ::: "memory");
      __syncthreads();   // also guards xs reuse (phase-X reads done)
      // ---- stage h_{t-1} -> xs (bf16). Agent-relaxed 8B atomic loads (sc1):
      //      coherent by construction, no cache maintenance needed. ----
      const unsigned short* hsrc = hbuf + ((size_t)((t - 1) & 1)) * (BAT * HID);
      for (int it = tid; it < BAT * HID / 4; it += 256) {
        int m = it >> 7;               // batch row
        int k = (it & 127) * 4;        // 4 bf16 = 8 B
        u64 v = __hip_atomic_load((const u64*)(hsrc + m * HID + k),
                                  __ATOMIC_RELAXED, __HIP_MEMORY_SCOPE_AGENT);
        *(u64*)(xs + m * XSS + k) = v;
      }
      __syncthreads();
      // ---- phase H: gates += h_{t-1} @ W_hh_slice^T ----
      const unsigned short* b0 = Wh + l15 * WSS + lg * 8;
      const unsigned short* b1 = Wh + (16 + l15) * WSS + lg * 8;
      #pragma unroll
      for (int kc = 0; kc < HID; kc += 32) {
        v8s a  = *(const v8s*)(aptr + kc);
        v8s w0 = *(const v8s*)(b0 + kc);
        v8s w1 = *(const v8s*)(b1 + kc);
        acc0 = __builtin_amdgcn_mfma_f32_16x16x32_bf16(a, w0, acc0, 0, 0, 0);
        acc1 = __builtin_amdgcn_mfma_f32_16x16x32_bf16(a, w1, acc1, 0, 0, 0);
      }
    }
    // ---- epilogue: C-frags -> gl.  C/D layout: col=lane&15, row=(lane>>4)*4+reg ----
    {
      int mrow = m0 + lg * 4;
      #pragma unroll
      for (int r = 0; r < 4; ++r) {
        gl[(mrow + r) * (NG + 1) + l15]      = acc0[r];
        gl[(mrow + r) * (NG + 1) + 16 + l15] = acc1[r];
      }
    }
    __syncthreads();
    // ---- cell update: 128 threads x 4 cells (one 8B h-publish per thread) ----
    unsigned short* hdst = hbuf + ((size_t)(t & 1)) * (BAT * HID);
    const int m  = tid >> 1;           // batch row 0..63
    const int h0 = (tid & 1) * 4;      // hidden sub-slice 0 or 4
    float hv[4], cv[4];
    if (tid < 128) {
      const float* gr = gl + m * (NG + 1);
      #pragma unroll
      for (int r = 0; r < 4; ++r) {
        int hh = h0 + r;
        float gi = gr[hh]      + bias[hh];
        float gf = gr[8 + hh]  + bias[8 + hh];
        float gg = gr[16 + hh] + bias[16 + hh];
        float go = gr[24 + hh] + bias[24 + hh];
        float c  = sigm(gf) * cs[m * CSS + hh] + sigm(gi) * tanha(gg);
        cs[m * CSS + hh] = c;
        cv[r] = c;
        hv[r] = sigm(go) * tanha(c);
      }
      // publish h slice: one relaxed agent-scope 8B atomic (sc1 write-through;
      // ack = visible at coherence point, so the barrier's vmcnt(0) drain
      // guarantees visibility before the flag store below).
      u64 pk =  (u64)f2bf(hv[0])
             | ((u64)f2bf(hv[1]) << 16)
             | ((u64)f2bf(hv[2]) << 32)
             | ((u64)f2bf(hv[3]) << 48);
      __hip_atomic_store((u64*)(hdst + m * HID + hb + h0), pk,
                         __ATOMIC_RELAXED, __HIP_MEMORY_SCOPE_AGENT);
    }
    asm volatile("" ::: "memory");
    __syncthreads();   // per-wave vmcnt(0) drain + barrier => h globally visible
    if (tid == 0) {
      __hip_atomic_store(flags + t * NWG + j, t + 1, __ATOMIC_RELAXED,
                         __HIP_MEMORY_SCOPE_AGENT);
    }
    // ---- out stores AFTER the publish: off the recurrence critical path;
    //      their drain overlaps next step's x staging. ----
    if (tid < 128) {
      size_t o = ((size_t)t * BAT + m) * HID + hb + h0;
      *(float4*)(out + o) = make_float4(hv[0], hv[1], hv[2], hv[3]);
      *(float4*)(out + (size_t)SEQ * BAT * HID + o) = make_float4(cv[0], cv[1], cv[2], cv[3]);
    }
  }
}

extern "C" void kernel_launch(void* const* d_in, const int* in_sizes, int n_in,
                              void* d_out, int out_size, void* d_ws, size_t ws_size,
                              hipStream_t stream) {
  const float* x   = (const float*)d_in[0];
  const float* Wih = (const float*)d_in[1];
  const float* Whh = (const float*)d_in[2];
  const float* bih = (const float*)d_in[3];
  const float* bhh = (const float*)d_in[4];
  float* out = (float*)d_out;

  int* flags = (int*)d_ws;                                        // SEQ*NWG ints = 512 KB
  unsigned short* hbuf =
      (unsigned short*)((char*)d_ws + (size_t)SEQ * NWG * sizeof(int));  // 2*64*512 bf16 = 128 KB

  // Clear flags (don't rely on 0xAA poison between graph replays).
  hipMemsetAsync(d_ws, 0, (size_t)SEQ * NWG * sizeof(int), stream);

  hipLaunchKernelGGL(lstm_persistent, dim3(NWG), dim3(256), 0, stream,
                     x, Wih, Whh, bih, bhh, out, flags, hbuf);
}

// Round 2
// 19009.280 us; speedup vs baseline: 2.3205x; 2.0139x over previous
//
#include <hip/hip_runtime.h>
#include <hip/hip_bf16.h>

// LSTM persistent-kernel implementation for MI355X (gfx950).
// S=2048 sequential steps; 64 WGs (1/CU), WG j owns hidden slice [8j, 8j+8).
// Weights (32 gate rows x 1024 K) cached in LDS as bf16 for the whole kernel.
//
// R2: barrier-free per-wave dataflow.
//  - No activation staging: x read global->reg (fp32->bf16 in-reg); h read
//    directly from hbuf via relaxed agent-scope 8B loads (sc1). Within a WG
//    every staged activation element was read exactly once -> LDS staging
//    bought nothing and cost 3 barriers + conversion passes + bank conflicts.
//  - Each wave owns 16 batch rows end-to-end (MFMA, epilogue, cell update,
//    publish). gl/cs rows are wave-private -> zero __syncthreads in the loop.
//  - Sync: one counter per step. Producer wave: sc1 h-store, s_waitcnt
//    vmcnt(0) drain, fire-and-forget atomic_add. Consumer: poll ONE word
//    (64 lanes same addr = 1 merged request/wave) instead of 64 flags x
//    4096 lanes. counter[t]==256 also proves all phase-H reads of h[t-1]
//    are done -> double-buffer parity reuse is safe.

#define SEQ 2048
#define BAT 64
#define DIN 512
#define HID 512
#define NWG 64
#define HS  8          // hidden units per WG
#define NG  32         // gate rows per WG (4*HS)
#define WSS 520        // weight row stride in bf16 elems (+8 pad)
#define GLS 34         // gl row stride in floats (even -> 8B-aligned float2)
#define CSS 10         // cs row stride in floats
#define NWAVES 256u    // total waves chip-wide (64 WGs x 4)

typedef short v8s __attribute__((ext_vector_type(8)));   // 8 x bf16 (4 VGPRs)
typedef float v4f __attribute__((ext_vector_type(4)));   // MFMA accumulator
typedef unsigned long long u64;

__device__ __forceinline__ unsigned short f2bf(float f) {
  unsigned int u = __builtin_bit_cast(unsigned int, f);
  u += 0x7fffu + ((u >> 16) & 1u);   // round-to-nearest-even
  return (unsigned short)(u >> 16);
}
__device__ __forceinline__ float sigm(float v)  { return 1.0f / (1.0f + __expf(-v)); }
__device__ __forceinline__ float tanha(float v) { return 1.0f - 2.0f / (__expf(2.0f * v) + 1.0f); }

__global__ __launch_bounds__(256, 1) void lstm_persistent(
    const float* __restrict__ x, const float* __restrict__ Wih,
    const float* __restrict__ Whh, const float* __restrict__ bih,
    const float* __restrict__ bhh, float* __restrict__ out,
    unsigned int* __restrict__ flags, unsigned short* __restrict__ hbuf)
{
  __shared__ unsigned short Wx[NG * WSS];      // 33,280 B: W_ih slice (bf16)
  __shared__ unsigned short Wh[NG * WSS];      // 33,280 B: W_hh slice (bf16)
  __shared__ float gl[BAT * GLS];              //  8,704 B: gate pre-activations
  __shared__ float cs[BAT * CSS];              //  2,560 B: c state (fp32)
  __shared__ float bias[NG];

  const int tid = threadIdx.x;
  const int j   = blockIdx.x;
  const int hb  = j * HS;

  // ---- one-time: load weight slices (rows: c = g*8+hh -> global row g*512+hb+hh) ----
  for (int idx = tid; idx < NG * 128; idx += 256) {
    int r = idx >> 7;              // 0..31
    int k = (idx & 127) * 4;       // 0..508
    int grow = (r >> 3) * HID + hb + (r & 7);
    float4 a = *(const float4*)(Wih + (size_t)grow * DIN + k);
    float4 b = *(const float4*)(Whh + (size_t)grow * HID + k);
    *(ushort4*)(Wx + r * WSS + k) = make_ushort4(f2bf(a.x), f2bf(a.y), f2bf(a.z), f2bf(a.w));
    *(ushort4*)(Wh + r * WSS + k) = make_ushort4(f2bf(b.x), f2bf(b.y), f2bf(b.z), f2bf(b.w));
  }
  if (tid < NG) {
    int grow = (tid >> 3) * HID + hb + (tid & 7);
    bias[tid] = bih[grow] + bhh[grow];
  }
  for (int i = tid; i < BAT * CSS; i += 256) cs[i] = 0.0f;
  __syncthreads();   // the ONLY barrier: weights/bias visible to all waves

  const int wv = tid >> 6, ln = tid & 63, l15 = ln & 15, lg = ln >> 4;
  const int m0 = wv * 16;                  // wave owns batch rows [m0, m0+16)
  const unsigned short* Wxp0 = Wx + l15 * WSS + lg * 8;
  const unsigned short* Wxp1 = Wx + (16 + l15) * WSS + lg * 8;
  const unsigned short* Whp0 = Wh + l15 * WSS + lg * 8;
  const unsigned short* Whp1 = Wh + (16 + l15) * WSS + lg * 8;
  // cell-update mapping: 2 adjacent hidden units per lane
  const int cm = m0 + (ln >> 2);           // batch row
  const int ch = (ln & 3) * 2;             // hidden pair base (0,2,4,6)

  for (int t = 0; t < SEQ; ++t) {
    v4f acc0 = {0.f, 0.f, 0.f, 0.f}, acc1 = {0.f, 0.f, 0.f, 0.f};

    // ---- phase X: gates += x_t @ W_ih_slice^T, x direct global->reg ----
    {
      const float* xr = x + ((size_t)t * BAT + m0 + l15) * DIN + lg * 8;
      #pragma unroll
      for (int kc = 0; kc < DIN; kc += 32) {
        float4 u0 = *(const float4*)(xr + kc);
        float4 u1 = *(const float4*)(xr + kc + 4);
        v8s a = { (short)f2bf(u0.x), (short)f2bf(u0.y), (short)f2bf(u0.z), (short)f2bf(u0.w),
                  (short)f2bf(u1.x), (short)f2bf(u1.y), (short)f2bf(u1.z), (short)f2bf(u1.w) };
        acc0 = __builtin_amdgcn_mfma_f32_16x16x32_bf16(a, *(const v8s*)(Wxp0 + kc), acc0, 0, 0, 0);
        acc1 = __builtin_amdgcn_mfma_f32_16x16x32_bf16(a, *(const v8s*)(Wxp1 + kc), acc1, 0, 0, 0);
      }
    }

    if (t > 0) {
      // ---- wait for step t-1 complete: poll ONE counter (merged request) ----
      while (__hip_atomic_load(flags + (t - 1), __ATOMIC_RELAXED,
                               __HIP_MEMORY_SCOPE_AGENT) < NWAVES) {
        __builtin_amdgcn_s_sleep(1);
      }
      asm volatile("" ::: "memory");   // pin h-loads after the poll
      // ---- phase H: h_{t-1} direct global(sc1)->reg, 16-deep pipelined ----
      const unsigned short* hr = hbuf + ((size_t)((t - 1) & 1)) * (BAT * HID)
                               + (size_t)(m0 + l15) * HID + lg * 8;
      #pragma unroll
      for (int kc = 0; kc < HID; kc += 32) {
        u64 q0 = __hip_atomic_load((const u64*)(hr + kc),     __ATOMIC_RELAXED, __HIP_MEMORY_SCOPE_AGENT);
        u64 q1 = __hip_atomic_load((const u64*)(hr + kc + 4), __ATOMIC_RELAXED, __HIP_MEMORY_SCOPE_AGENT);
        union { u64 q[2]; v8s a; } U;
        U.q[0] = q0; U.q[1] = q1;
        acc0 = __builtin_amdgcn_mfma_f32_16x16x32_bf16(U.a, *(const v8s*)(Whp0 + kc), acc0, 0, 0, 0);
        acc1 = __builtin_amdgcn_mfma_f32_16x16x32_bf16(U.a, *(const v8s*)(Whp1 + kc), acc1, 0, 0, 0);
      }
    }

    // ---- epilogue: C-frags -> gl (wave-private rows; lgkmcnt ordering only).
    //      C/D layout: col=lane&15, row=(lane>>4)*4+reg ----
    {
      int mrow = m0 + lg * 4;
      #pragma unroll
      for (int r = 0; r < 4; ++r) {
        gl[(mrow + r) * GLS + l15]      = acc0[r];
        gl[(mrow + r) * GLS + 16 + l15] = acc1[r];
      }
    }

    // ---- cell update: 2 cells per lane, all wave-local ----
    float2 hv, cv;
    {
      const float* gr = gl + cm * GLS;
      float* csp = cs + cm * CSS + ch;
      #pragma unroll
      for (int r = 0; r < 2; ++r) {
        int hh = ch + r;
        float gi = gr[hh]      + bias[hh];
        float gf = gr[8 + hh]  + bias[8 + hh];
        float gg = gr[16 + hh] + bias[16 + hh];
        float go = gr[24 + hh] + bias[24 + hh];
        float c  = sigm(gf) * csp[r] + sigm(gi) * tanha(gg);
        csp[r] = c;
        (&cv.x)[r] = c;
        (&hv.x)[r] = sigm(go) * tanha(c);
      }
    }

    // ---- publish h pair (sc1 4B store), drain, fire-and-forget counter add ----
    {
      unsigned int hp = (unsigned int)f2bf(hv.x) | ((unsigned int)f2bf(hv.y) << 16);
      unsigned short* hd = hbuf + ((size_t)(t & 1)) * (BAT * HID)
                         + (size_t)cm * HID + hb + ch;
      __hip_atomic_store((unsigned int*)hd, hp, __ATOMIC_RELAXED,
                         __HIP_MEMORY_SCOPE_AGENT);
    }
    asm volatile("s_waitcnt vmcnt(0)" ::: "memory");  // sc1 store ack'd at coherence point
    if (ln == 0) {
      __hip_atomic_fetch_add(flags + t, 1u, __ATOMIC_RELAXED,
                             __HIP_MEMORY_SCOPE_AGENT);
    }

    // ---- out stores AFTER the publish: off the recurrence critical path ----
    {
      size_t o = ((size_t)t * BAT + cm) * HID + hb + ch;
      *(float2*)(out + o) = hv;
      *(float2*)(out + (size_t)SEQ * BAT * HID + o) = cv;
    }
  }
}

extern "C" void kernel_launch(void* const* d_in, const int* in_sizes, int n_in,
                              void* d_out, int out_size, void* d_ws, size_t ws_size,
                              hipStream_t stream) {
  const float* x   = (const float*)d_in[0];
  const float* Wih = (const float*)d_in[1];
  const float* Whh = (const float*)d_in[2];
  const float* bih = (const float*)d_in[3];
  const float* bhh = (const float*)d_in[4];
  float* out = (float*)d_out;

  unsigned int* flags = (unsigned int*)d_ws;                      // SEQ counters = 8 KB
  unsigned short* hbuf =
      (unsigned short*)((char*)d_ws + (size_t)SEQ * sizeof(unsigned int));  // 2*64*512 bf16 = 128 KB

  // Clear counters (don't rely on 0xAA poison between graph replays).
  hipMemsetAsync(d_ws, 0, (size_t)SEQ * sizeof(unsigned int), stream);

  hipLaunchKernelGGL(lstm_persistent, dim3(NWG), dim3(256), 0, stream,
                     x, Wih, Whh, bih, bhh, out, flags, hbuf);
}

// Round 3
// 14637.842 us; speedup vs baseline: 3.0135x; 1.2986x over previous
//
#include <hip/hip_runtime.h>
#include <hip/hip_bf16.h>

// LSTM for MI355X (gfx950) — R3: two-phase (x-projection GEMM + persistent recurrence).
//
// Phase 1 (gemm_xproj, 512 WGs): xp[s][j][b][g] = x[s] @ Wih_slice_j^T, bf16,
//   512 MB in workspace. Mirrors the reference, which precomputes x_proj before
//   the scan. Removes from the 2048-step serial chain: per-step x HBM fetch,
//   128 f2bf conversions, and half the MFMAs.
// Phase 2 (lstm_recur, 64 WGs persistent): per step = poll -> 32 MFMA (h@Whh)
//   -> cell update (gates = accH + bias + xp). xp loads issued BEFORE the poll
//   (precomputed, infinitely prefetchable).
// Sync: per-WG flag words (plain sc1 stores after __syncthreads; no atomic RMW
//   contention). Consumer: one 64-lane vector load + __ballot per poll.
// Fallback: if ws_size < 537.5 MB, launch the R2 single-kernel path verbatim.

#define SEQ 2048
#define BAT 64
#define DIN 512
#define HID 512
#define NWG 64
#define HS  8          // hidden units per WG
#define NG  32         // gate rows per WG (4*HS)
#define WSS 520        // weight row stride in bf16 elems (+8 pad)
#define GLS 34         // gl row stride in floats
#define CSS 10         // cs row stride in floats
#define JG  4          // j-slices per GEMM WG
#define NJG (NWG / JG) // 16
#define SCH 64         // timesteps per GEMM chunk
#define NCH (SEQ / SCH)// 32
#define NWAVES 256u

typedef short v8s __attribute__((ext_vector_type(8)));   // 8 x bf16 (4 VGPRs)
typedef float v4f __attribute__((ext_vector_type(4)));   // MFMA accumulator
typedef unsigned long long u64;

__device__ __forceinline__ unsigned short f2bf(float f) {
  unsigned int u = __builtin_bit_cast(unsigned int, f);
  u += 0x7fffu + ((u >> 16) & 1u);   // round-to-nearest-even
  return (unsigned short)(u >> 16);
}
__device__ __forceinline__ float bf2f(unsigned short u) {
  unsigned int v = ((unsigned int)u) << 16;
  return __builtin_bit_cast(float, v);
}
__device__ __forceinline__ float sigm(float v)  { return 1.0f / (1.0f + __expf(-v)); }
__device__ __forceinline__ float tanha(float v) { return 1.0f - 2.0f / (__expf(2.0f * v) + 1.0f); }

// ---------------- Phase 1: x-projection GEMM ----------------
// grid = NCH*NJG; bid = ch*NJG + jg (chunk-major: the 16 WGs sharing a chunk
// are consecutive -> concurrent -> x[s] served from L2/L3, not re-fetched).
__global__ __launch_bounds__(256, 1) void gemm_xproj(
    const float* __restrict__ x, const float* __restrict__ Wih,
    unsigned short* __restrict__ xp)
{
  __shared__ unsigned short Wx[JG * NG * WSS];   // 133,120 B

  const int tid = threadIdx.x;
  const int jg  = blockIdx.x % NJG;
  const int ch  = blockIdx.x / NJG;

  for (int idx = tid; idx < JG * NG * 128; idx += 256) {
    int r = idx >> 7;              // 0..127 = jj*32 + rr
    int k = (idx & 127) * 4;
    int jj = r >> 5, rr = r & 31;
    int grow = (rr >> 3) * HID + (jg * JG + jj) * HS + (rr & 7);
    float4 a = *(const float4*)(Wih + (size_t)grow * DIN + k);
    *(ushort4*)(Wx + r * WSS + k) = make_ushort4(f2bf(a.x), f2bf(a.y), f2bf(a.z), f2bf(a.w));
  }
  __syncthreads();

  const int wv = tid >> 6, ln = tid & 63, l15 = ln & 15, lg = ln >> 4;
  const int m0 = wv * 16;
  const unsigned short* Bp00 = Wx + (0 * NG + l15) * WSS + lg * 8;
  const unsigned short* Bp01 = Wx + (0 * NG + 16 + l15) * WSS + lg * 8;
  const unsigned short* Bp10 = Wx + (1 * NG + l15) * WSS + lg * 8;
  const unsigned short* Bp11 = Wx + (1 * NG + 16 + l15) * WSS + lg * 8;
  const unsigned short* Bp20 = Wx + (2 * NG + l15) * WSS + lg * 8;
  const unsigned short* Bp21 = Wx + (2 * NG + 16 + l15) * WSS + lg * 8;
  const unsigned short* Bp30 = Wx + (3 * NG + l15) * WSS + lg * 8;
  const unsigned short* Bp31 = Wx + (3 * NG + 16 + l15) * WSS + lg * 8;

  for (int s = ch * SCH; s < ch * SCH + SCH; ++s) {
    v4f a00 = {0,0,0,0}, a01 = {0,0,0,0}, a10 = {0,0,0,0}, a11 = {0,0,0,0};
    v4f a20 = {0,0,0,0}, a21 = {0,0,0,0}, a30 = {0,0,0,0}, a31 = {0,0,0,0};
    const float* xr = x + ((size_t)s * BAT + m0 + l15) * DIN + lg * 8;
    #pragma unroll
    for (int kc = 0; kc < DIN; kc += 32) {
      float4 u0 = *(const float4*)(xr + kc);
      float4 u1 = *(const float4*)(xr + kc + 4);
      v8s a = { (short)f2bf(u0.x), (short)f2bf(u0.y), (short)f2bf(u0.z), (short)f2bf(u0.w),
                (short)f2bf(u1.x), (short)f2bf(u1.y), (short)f2bf(u1.z), (short)f2bf(u1.w) };
      a00 = __builtin_amdgcn_mfma_f32_16x16x32_bf16(a, *(const v8s*)(Bp00 + kc), a00, 0, 0, 0);
      a01 = __builtin_amdgcn_mfma_f32_16x16x32_bf16(a, *(const v8s*)(Bp01 + kc), a01, 0, 0, 0);
      a10 = __builtin_amdgcn_mfma_f32_16x16x32_bf16(a, *(const v8s*)(Bp10 + kc), a10, 0, 0, 0);
      a11 = __builtin_amdgcn_mfma_f32_16x16x32_bf16(a, *(const v8s*)(Bp11 + kc), a11, 0, 0, 0);
      a20 = __builtin_amdgcn_mfma_f32_16x16x32_bf16(a, *(const v8s*)(Bp20 + kc), a20, 0, 0, 0);
      a21 = __builtin_amdgcn_mfma_f32_16x16x32_bf16(a, *(const v8s*)(Bp21 + kc), a21, 0, 0, 0);
      a30 = __builtin_amdgcn_mfma_f32_16x16x32_bf16(a, *(const v8s*)(Bp30 + kc), a30, 0, 0, 0);
      a31 = __builtin_amdgcn_mfma_f32_16x16x32_bf16(a, *(const v8s*)(Bp31 + kc), a31, 0, 0, 0);
    }
    // epilogue: C/D layout col=lane&15, row=(lane>>4)*4+reg.  xp[s][jw][b][g].
    #pragma unroll
    for (int jj = 0; jj < JG; ++jj) {
      const v4f* A0 = (jj == 0) ? &a00 : (jj == 1) ? &a10 : (jj == 2) ? &a20 : &a30;
      const v4f* A1 = (jj == 0) ? &a01 : (jj == 1) ? &a11 : (jj == 2) ? &a21 : &a31;
      size_t base = (((size_t)s * NWG + (jg * JG + jj)) * BAT + m0 + lg * 4) * NG;
      #pragma unroll
      for (int r = 0; r < 4; ++r) {
        unsigned short* p = xp + base + (size_t)r * NG;
        p[l15]      = f2bf((*A0)[r]);
        p[16 + l15] = f2bf((*A1)[r]);
      }
    }
  }
}

// ---------------- Phase 2: persistent recurrence ----------------
__global__ __launch_bounds__(256, 1) void lstm_recur(
    const float* __restrict__ Whh, const float* __restrict__ bih,
    const float* __restrict__ bhh, const unsigned short* __restrict__ xp,
    float* __restrict__ out, unsigned int* __restrict__ flags,
    unsigned short* __restrict__ hbuf)
{
  __shared__ unsigned short Wh[NG * WSS];      // 33,280 B
  __shared__ float gl[BAT * GLS];              //  8,704 B
  __shared__ float cs[BAT * CSS];              //  2,560 B
  __shared__ float bias[NG];

  const int tid = threadIdx.x;
  const int j   = blockIdx.x;
  const int hb  = j * HS;

  for (int idx = tid; idx < NG * 128; idx += 256) {
    int r = idx >> 7;
    int k = (idx & 127) * 4;
    int grow = (r >> 3) * HID + hb + (r & 7);
    float4 b = *(const float4*)(Whh + (size_t)grow * HID + k);
    *(ushort4*)(Wh + r * WSS + k) = make_ushort4(f2bf(b.x), f2bf(b.y), f2bf(b.z), f2bf(b.w));
  }
  if (tid < NG) {
    int grow = (tid >> 3) * HID + hb + (tid & 7);
    bias[tid] = bih[grow] + bhh[grow];
  }
  for (int i = tid; i < BAT * CSS; i += 256) cs[i] = 0.0f;
  __syncthreads();

  const int wv = tid >> 6, ln = tid & 63, l15 = ln & 15, lg = ln >> 4;
  const int m0 = wv * 16;
  const unsigned short* Whp0 = Wh + l15 * WSS + lg * 8;
  const unsigned short* Whp1 = Wh + (16 + l15) * WSS + lg * 8;
  const int cm = m0 + (ln >> 2);           // batch row for cell update
  const int ch = (ln & 3) * 2;             // hidden pair base

  for (int t = 0; t < SEQ; ++t) {
    // ---- xp loads for this step: issued BEFORE the poll (precomputed data) ----
    const unsigned short* xpb = xp + (((size_t)t * NWG + j) * BAT + cm) * NG + ch;
    unsigned int xgi = *(const unsigned int*)(xpb);
    unsigned int xgf = *(const unsigned int*)(xpb + 8);
    unsigned int xgg = *(const unsigned int*)(xpb + 16);
    unsigned int xgo = *(const unsigned int*)(xpb + 24);

    v4f acc0 = {0.f, 0.f, 0.f, 0.f}, acc1 = {0.f, 0.f, 0.f, 0.f};
    if (t > 0) {
      // ---- poll: 64 per-WG flags with one vector load + ballot ----
      const unsigned int* fp = flags + (size_t)(t - 1) * NWG + ln;
      for (;;) {
        unsigned int fv = __hip_atomic_load(fp, __ATOMIC_RELAXED,
                                            __HIP_MEMORY_SCOPE_AGENT);
        if (__ballot(fv == (unsigned int)t) == ~0ull) break;
        __builtin_amdgcn_s_sleep(1);
      }
      asm volatile("" ::: "memory");   // pin h-loads after the poll
      // ---- phase H: h_{t-1} direct global(sc1)->reg ----
      const unsigned short* hr = hbuf + ((size_t)((t - 1) & 1)) * (BAT * HID)
                               + (size_t)(m0 + l15) * HID + lg * 8;
      #pragma unroll
      for (int kc = 0; kc < HID; kc += 32) {
        u64 q0 = __hip_atomic_load((const u64*)(hr + kc),     __ATOMIC_RELAXED, __HIP_MEMORY_SCOPE_AGENT);
        u64 q1 = __hip_atomic_load((const u64*)(hr + kc + 4), __ATOMIC_RELAXED, __HIP_MEMORY_SCOPE_AGENT);
        union { u64 q[2]; v8s a; } U;
        U.q[0] = q0; U.q[1] = q1;
        acc0 = __builtin_amdgcn_mfma_f32_16x16x32_bf16(U.a, *(const v8s*)(Whp0 + kc), acc0, 0, 0, 0);
        acc1 = __builtin_amdgcn_mfma_f32_16x16x32_bf16(U.a, *(const v8s*)(Whp1 + kc), acc1, 0, 0, 0);
      }
    }

    // ---- epilogue: C-frags -> gl (wave-private rows, lgkmcnt ordering only) ----
    {
      int mrow = m0 + lg * 4;
      #pragma unroll
      for (int r = 0; r < 4; ++r) {
        gl[(mrow + r) * GLS + l15]      = acc0[r];
        gl[(mrow + r) * GLS + 16 + l15] = acc1[r];
      }
    }

    // ---- cell update: 2 cells per lane (explicit r=0/r=1, static indexing) ----
    float2 hv, cv;
    {
      const float* gr = gl + cm * GLS;
      float* csp = cs + cm * CSS + ch;
      float xi0 = bf2f((unsigned short)(xgi & 0xffffu)), xi1 = bf2f((unsigned short)(xgi >> 16));
      float xf0 = bf2f((unsigned short)(xgf & 0xffffu)), xf1 = bf2f((unsigned short)(xgf >> 16));
      float xg0 = bf2f((unsigned short)(xgg & 0xffffu)), xg1 = bf2f((unsigned short)(xgg >> 16));
      float xo0 = bf2f((unsigned short)(xgo & 0xffffu)), xo1 = bf2f((unsigned short)(xgo >> 16));
      // r = 0
      {
        float gi = gr[ch]      + bias[ch]      + xi0;
        float gf = gr[8 + ch]  + bias[8 + ch]  + xf0;
        float gg = gr[16 + ch] + bias[16 + ch] + xg0;
        float go = gr[24 + ch] + bias[24 + ch] + xo0;
        float c  = sigm(gf) * csp[0] + sigm(gi) * tanha(gg);
        csp[0] = c; cv.x = c; hv.x = sigm(go) * tanha(c);
      }
      // r = 1
      {
        int hh = ch + 1;
        float gi = gr[hh]      + bias[hh]      + xi1;
        float gf = gr[8 + hh]  + bias[8 + hh]  + xf1;
        float gg = gr[16 + hh] + bias[16 + hh] + xg1;
        float go = gr[24 + hh] + bias[24 + hh] + xo1;
        float c  = sigm(gf) * csp[1] + sigm(gi) * tanha(gg);
        csp[1] = c; cv.y = c; hv.y = sigm(go) * tanha(c);
      }
    }

    // ---- publish h pair (sc1), WG-drain via barrier, per-WG flag store ----
    {
      unsigned int hp = (unsigned int)f2bf(hv.x) | ((unsigned int)f2bf(hv.y) << 16);
      unsigned short* hd = hbuf + ((size_t)(t & 1)) * (BAT * HID)
                         + (size_t)cm * HID + hb + ch;
      __hip_atomic_store((unsigned int*)hd, hp, __ATOMIC_RELAXED,
                         __HIP_MEMORY_SCOPE_AGENT);
    }
    __syncthreads();   // each wave drains vmcnt(0) before barrier => all h at L3
    if (tid == 0) {
      __hip_atomic_store(flags + (size_t)t * NWG + j, (unsigned int)(t + 1),
                         __ATOMIC_RELAXED, __HIP_MEMORY_SCOPE_AGENT);
    }

    // ---- out stores AFTER the publish: off the recurrence critical path ----
    {
      size_t o = ((size_t)t * BAT + cm) * HID + hb + ch;
      *(float2*)(out + o) = hv;
      *(float2*)(out + (size_t)SEQ * BAT * HID + o) = cv;
    }
  }
}

// ---------------- R2 fallback (single persistent kernel) ----------------
__global__ __launch_bounds__(256, 1) void lstm_fallback(
    const float* __restrict__ x, const float* __restrict__ Wih,
    const float* __restrict__ Whh, const float* __restrict__ bih,
    const float* __restrict__ bhh, float* __restrict__ out,
    unsigned int* __restrict__ flags, unsigned short* __restrict__ hbuf)
{
  __shared__ unsigned short Wx[NG * WSS];
  __shared__ unsigned short Wh[NG * WSS];
  __shared__ float gl[BAT * GLS];
  __shared__ float cs[BAT * CSS];
  __shared__ float bias[NG];

  const int tid = threadIdx.x;
  const int j   = blockIdx.x;
  const int hb  = j * HS;

  for (int idx = tid; idx < NG * 128; idx += 256) {
    int r = idx >> 7;
    int k = (idx & 127) * 4;
    int grow = (r >> 3) * HID + hb + (r & 7);
    float4 a = *(const float4*)(Wih + (size_t)grow * DIN + k);
    float4 b = *(const float4*)(Whh + (size_t)grow * HID + k);
    *(ushort4*)(Wx + r * WSS + k) = make_ushort4(f2bf(a.x), f2bf(a.y), f2bf(a.z), f2bf(a.w));
    *(ushort4*)(Wh + r * WSS + k) = make_ushort4(f2bf(b.x), f2bf(b.y), f2bf(b.z), f2bf(b.w));
  }
  if (tid < NG) {
    int grow = (tid >> 3) * HID + hb + (tid & 7);
    bias[tid] = bih[grow] + bhh[grow];
  }
  for (int i = tid; i < BAT * CSS; i += 256) cs[i] = 0.0f;
  __syncthreads();

  const int wv = tid >> 6, ln = tid & 63, l15 = ln & 15, lg = ln >> 4;
  const int m0 = wv * 16;
  const unsigned short* Wxp0 = Wx + l15 * WSS + lg * 8;
  const unsigned short* Wxp1 = Wx + (16 + l15) * WSS + lg * 8;
  const unsigned short* Whp0 = Wh + l15 * WSS + lg * 8;
  const unsigned short* Whp1 = Wh + (16 + l15) * WSS + lg * 8;
  const int cm = m0 + (ln >> 2);
  const int ch = (ln & 3) * 2;

  for (int t = 0; t < SEQ; ++t) {
    v4f acc0 = {0.f, 0.f, 0.f, 0.f}, acc1 = {0.f, 0.f, 0.f, 0.f};
    {
      const float* xr = x + ((size_t)t * BAT + m0 + l15) * DIN + lg * 8;
      #pragma unroll
      for (int kc = 0; kc < DIN; kc += 32) {
        float4 u0 = *(const float4*)(xr + kc);
        float4 u1 = *(const float4*)(xr + kc + 4);
        v8s a = { (short)f2bf(u0.x), (short)f2bf(u0.y), (short)f2bf(u0.z), (short)f2bf(u0.w),
                  (short)f2bf(u1.x), (short)f2bf(u1.y), (short)f2bf(u1.z), (short)f2bf(u1.w) };
        acc0 = __builtin_amdgcn_mfma_f32_16x16x32_bf16(a, *(const v8s*)(Wxp0 + kc), acc0, 0, 0, 0);
        acc1 = __builtin_amdgcn_mfma_f32_16x16x32_bf16(a, *(const v8s*)(Wxp1 + kc), acc1, 0, 0, 0);
      }
    }
    if (t > 0) {
      while (__hip_atomic_load(flags + (t - 1), __ATOMIC_RELAXED,
                               __HIP_MEMORY_SCOPE_AGENT) < NWAVES) {
        __builtin_amdgcn_s_sleep(1);
      }
      asm volatile("" ::: "memory");
      const unsigned short* hr = hbuf + ((size_t)((t - 1) & 1)) * (BAT * HID)
                               + (size_t)(m0 + l15) * HID + lg * 8;
      #pragma unroll
      for (int kc = 0; kc < HID; kc += 32) {
        u64 q0 = __hip_atomic_load((const u64*)(hr + kc),     __ATOMIC_RELAXED, __HIP_MEMORY_SCOPE_AGENT);
        u64 q1 = __hip_atomic_load((const u64*)(hr + kc + 4), __ATOMIC_RELAXED, __HIP_MEMORY_SCOPE_AGENT);
        union { u64 q[2]; v8s a; } U;
        U.q[0] = q0; U.q[1] = q1;
        acc0 = __builtin_amdgcn_mfma_f32_16x16x32_bf16(U.a, *(const v8s*)(Whp0 + kc), acc0, 0, 0, 0);
        acc1 = __builtin_amdgcn_mfma_f32_16x16x32_bf16(U.a, *(const v8s*)(Whp1 + kc), acc1, 0, 0, 0);
      }
    }
    {
      int mrow = m0 + lg * 4;
      #pragma unroll
      for (int r = 0; r < 4; ++r) {
        gl[(mrow + r) * GLS + l15]      = acc0[r];
        gl[(mrow + r) * GLS + 16 + l15] = acc1[r];
      }
    }
    float2 hv, cv;
    {
      const float* gr = gl + cm * GLS;
      float* csp = cs + cm * CSS + ch;
      #pragma unroll
      for (int r = 0; r < 2; ++r) {
        int hh = ch + r;
        float gi = gr[hh]      + bias[hh];
        float gf = gr[8 + hh]  + bias[8 + hh];
        float gg = gr[16 + hh] + bias[16 + hh];
        float go = gr[24 + hh] + bias[24 + hh];
        float c  = sigm(gf) * csp[r] + sigm(gi) * tanha(gg);
        csp[r] = c;
        (&cv.x)[r] = c;
        (&hv.x)[r] = sigm(go) * tanha(c);
      }
    }
    {
      unsigned int hp = (unsigned int)f2bf(hv.x) | ((unsigned int)f2bf(hv.y) << 16);
      unsigned short* hd = hbuf + ((size_t)(t & 1)) * (BAT * HID)
                         + (size_t)cm * HID + hb + ch;
      __hip_atomic_store((unsigned int*)hd, hp, __ATOMIC_RELAXED,
                         __HIP_MEMORY_SCOPE_AGENT);
    }
    asm volatile("s_waitcnt vmcnt(0)" ::: "memory");
    if (ln == 0) {
      __hip_atomic_fetch_add(flags + t, 1u, __ATOMIC_RELAXED,
                             __HIP_MEMORY_SCOPE_AGENT);
    }
    {
      size_t o = ((size_t)t * BAT + cm) * HID + hb + ch;
      *(float2*)(out + o) = hv;
      *(float2*)(out + (size_t)SEQ * BAT * HID + o) = cv;
    }
  }
}

extern "C" void kernel_launch(void* const* d_in, const int* in_sizes, int n_in,
                              void* d_out, int out_size, void* d_ws, size_t ws_size,
                              hipStream_t stream) {
  const float* x   = (const float*)d_in[0];
  const float* Wih = (const float*)d_in[1];
  const float* Whh = (const float*)d_in[2];
  const float* bih = (const float*)d_in[3];
  const float* bhh = (const float*)d_in[4];
  float* out = (float*)d_out;

  const size_t flags_b = (size_t)SEQ * NWG * sizeof(unsigned int);   // 512 KB
  const size_t hbuf_b  = (size_t)2 * BAT * HID * sizeof(unsigned short); // 128 KB
  const size_t xp_b    = (size_t)SEQ * NWG * BAT * NG * sizeof(unsigned short); // 512 MB

  if (ws_size >= flags_b + hbuf_b + xp_b) {
    unsigned int*  flags = (unsigned int*)d_ws;
    unsigned short* hbuf = (unsigned short*)((char*)d_ws + flags_b);
    unsigned short* xp   = (unsigned short*)((char*)d_ws + flags_b + hbuf_b);
    hipMemsetAsync(d_ws, 0, flags_b, stream);
    hipLaunchKernelGGL(gemm_xproj, dim3(NCH * NJG), dim3(256), 0, stream, x, Wih, xp);
    hipLaunchKernelGGL(lstm_recur, dim3(NWG), dim3(256), 0, stream,
                       Whh, bih, bhh, xp, out, flags, hbuf);
  } else {
    unsigned int*  flags = (unsigned int*)d_ws;                         // SEQ counters
    unsigned short* hbuf = (unsigned short*)((char*)d_ws + (size_t)SEQ * sizeof(unsigned int));
    hipMemsetAsync(d_ws, 0, (size_t)SEQ * sizeof(unsigned int), stream);
    hipLaunchKernelGGL(lstm_fallback, dim3(NWG), dim3(256), 0, stream,
                       x, Wih, Whh, bih, bhh, out, flags, hbuf);
  }
}